// Round 9
// baseline (96.326 us; speedup 1.0000x reference)
//
#include <hip/hip_runtime.h>
#include <hip/hip_bf16.h>

#define B_DIM 4096
#define I_DIM 2048
#define H_DIM 2048

typedef unsigned char u8;
typedef unsigned short u16;
typedef unsigned int u32;
typedef __attribute__((ext_vector_type(4))) float f32x4;
typedef __attribute__((ext_vector_type(4))) int i32x4;
typedef __attribute__((ext_vector_type(8))) int i32x8;

__device__ __forceinline__ void gload_lds16(const void* g, void* l) {
  __builtin_amdgcn_global_load_lds(
      (const __attribute__((address_space(1))) void*)g,
      (__attribute__((address_space(3))) void*)l, 16, 0, 0);
}

// branchless fp4 (e2m1) encoder: quantizes v*inv_scale to e2m1 code
__device__ __forceinline__ u32 f2fp4(float v, float inv_scale) {
  const float a = fabsf(v) * inv_scale;
  u32 m = (u32)(a > 0.25f) + (u32)(a > 0.75f) + (u32)(a > 1.25f) +
          (u32)(a > 1.75f) + (u32)(a > 2.5f) + (u32)(a > 3.5f) + (u32)(a > 5.0f);
  return ((__float_as_uint(v) >> 31) << 3) | m;
}

// ---------------------------------------------------------------------------
// Kernel A: x -> fp4 (scale 1) xf4[B, I/2 bytes];
//           (an,bn) -> fp4-pair byte ab4[I,H] (lo=an, hi=bn; x8, HW 2^-3)
// ---------------------------------------------------------------------------
__global__ void convert_ew(const float* __restrict__ x, const float* __restrict__ an,
                           const float* __restrict__ bn, u16* __restrict__ xf4,
                           u32* __restrict__ ab4) {
  const long NX4 = (long)B_DIM * I_DIM / 4;
  const long NA4 = (long)I_DIM * H_DIM / 4;
  const long total = NX4 + NA4;
  for (long t = (long)blockIdx.x * blockDim.x + threadIdx.x; t < total;
       t += (long)gridDim.x * blockDim.x) {
    if (t < NX4) {
      float4 v = *(const float4*)(x + t * 4);
      u32 b0 = f2fp4(v.x, 1.f) | (f2fp4(v.y, 1.f) << 4);
      u32 b1 = f2fp4(v.z, 1.f) | (f2fp4(v.w, 1.f) << 4);
      xf4[t] = (u16)(b0 | (b1 << 8));
    } else {
      long p = (t - NX4) * 4;
      float4 va = *(const float4*)(an + p);
      float4 vb = *(const float4*)(bn + p);
      u32 b0 = f2fp4(va.x, 8.f) | (f2fp4(vb.x, 8.f) << 4);
      u32 b1 = f2fp4(va.y, 8.f) | (f2fp4(vb.y, 8.f) << 4);
      u32 b2 = f2fp4(va.z, 8.f) | (f2fp4(vb.z, 8.f) << 4);
      u32 b3 = f2fp4(va.w, 8.f) | (f2fp4(vb.w, 8.f) << 4);
      ab4[p >> 2] = b0 | (b1 << 8) | (b2 << 16) | (b3 << 24);
    }
  }
}

// ---------------------------------------------------------------------------
// Kernel B: coeff [I,H] fp32 -> coeffT fp4 x8 (HW 2^-3), [H, I/2 bytes]
// ---------------------------------------------------------------------------
__global__ void transpose_conv(const float* __restrict__ c, u16* __restrict__ ct4) {
  __shared__ float tile[32][33];
  const int i0 = blockIdx.y * 32;
  const int h0 = blockIdx.x * 32;
  const int tid = threadIdx.x;
  const int tx = tid & 31;
  const int ty = tid >> 5;
  for (int r = ty; r < 32; r += 8)
    tile[r][tx] = c[(long)(i0 + r) * H_DIM + (h0 + tx)];
  __syncthreads();
  const int hl = tid >> 3;
  const int q = (tid & 7) * 4;
  u32 w = f2fp4(tile[q + 0][hl], 8.f) | (f2fp4(tile[q + 1][hl], 8.f) << 4) |
          (f2fp4(tile[q + 2][hl], 8.f) << 8) | (f2fp4(tile[q + 3][hl], 8.f) << 12);
  ct4[(long)(h0 + hl) * (I_DIM / 4) + ((i0 + q) >> 2)] = (u16)w;
}

// ---------------------------------------------------------------------------
// fp4 GEMM K-loop, reg-staged A: B in dbuf LDS (2x16KB, XOR-swizzled,
// single barrier/iter, depth-1 stage); A fragments global->VGPR with
// depth-1 named double-buffer prefetch (afA/afB, 2-step unrolled loop).
// 128x128 block, 4 waves (2x2), per-wave 64x64.
// ---------------------------------------------------------------------------
__device__ __forceinline__ void stageB(const char* Bb, long kbyte, long ldb,
                                       char* Bdst, int tid) {
#pragma unroll
  for (int i = 0; i < 4; ++i) {
    const int o = i * 4096 + tid * 16;
    const int row = o >> 7;
    const int ls = ((((o >> 4) & 7) ^ (row & 7)) << 4);
    gload_lds16(Bb + (long)row * ldb + kbyte + ls, Bdst + o);
  }
}

__device__ __forceinline__ i32x4 frag_ld16(const char* S, int row, int slot) {
  return *(const i32x4*)(S + row * 128 + ((slot ^ (row & 7)) << 4));
}

#define FS_ITER(CUR, NXT, t)                                                     \
  {                                                                              \
    asm volatile("s_waitcnt vmcnt(0)" ::: "memory");                             \
    __builtin_amdgcn_sched_barrier(0);                                           \
    __builtin_amdgcn_s_barrier();                                                \
    __builtin_amdgcn_sched_barrier(0);                                           \
    const char* Bs = BsB + (((t) & 1) << 14);                                    \
    i32x8 bfr[8];                                                                \
    _Pragma("unroll") for (int s = 0; s < 2; ++s)                                \
      _Pragma("unroll") for (int n = 0; n < 4; ++n)                              \
        *(i32x4*)&bfr[s * 4 + n] = frag_ld16(Bs, brow + n * 16, s * 4 + g);      \
    if ((t) + 1 < nt) {                                                          \
      const long kb = ((long)(t) + 1) * 128;                                     \
      _Pragma("unroll") for (int s = 0; s < 2; ++s)                              \
        _Pragma("unroll") for (int m = 0; m < 4; ++m)                            \
          *(i32x4*)&NXT[s * 4 + m] =                                             \
              *(const i32x4*)(Arow + (long)m * 16 * lda + kb + (s * 4 + g) * 16);\
      stageB(Bb, kb, ldb, BsB + ((((t) + 1) & 1) << 14), tid);                   \
    }                                                                            \
    __builtin_amdgcn_sched_barrier(0);                                           \
    asm volatile("s_waitcnt lgkmcnt(0)" ::: "memory");                           \
    __builtin_amdgcn_sched_barrier(0);                                           \
    __builtin_amdgcn_s_setprio(1);                                               \
    _Pragma("unroll") for (int s = 0; s < 2; ++s)                                \
      _Pragma("unroll") for (int m = 0; m < 4; ++m)                              \
        _Pragma("unroll") for (int n = 0; n < 4; ++n)                            \
          acc[m][n] = __builtin_amdgcn_mfma_scale_f32_16x16x128_f8f6f4(          \
              CUR[s * 4 + m], bfr[s * 4 + n], acc[m][n], 4, 4, 0, SA, 0, SB);    \
    __builtin_amdgcn_s_setprio(0);                                               \
    __builtin_amdgcn_sched_barrier(0);                                           \
  }

template <int SA, int SB>
__device__ __forceinline__ void gemm_kloop_fp4(const char* __restrict__ A,
                                               const char* __restrict__ Bt,
                                               int rowA0, int colB0, long Kbytes,
                                               char* BsB, f32x4 acc[4][4]) {
  const int tid = threadIdx.x;
  const int lane = tid & 63;
  const int wid = tid >> 6;
  const int wr = wid >> 1, wc = wid & 1;
  const long lda = Kbytes, ldb = Kbytes;
  const char* Bb = Bt + (long)colB0 * ldb;
  const char* Arow = A + (long)(rowA0 + wr * 64 + (lane & 15)) * lda;
  const int brow = wc * 64 + (lane & 15);
  const int g = lane >> 4;  // 0..3
  const int nt = (int)(Kbytes >> 7);

  i32x8 afA[8], afB[8];
  // prologue: A frags (t=0) to regs, B tile 0 to LDS buf0
#pragma unroll
  for (int s = 0; s < 2; ++s)
#pragma unroll
    for (int m = 0; m < 4; ++m)
      *(i32x4*)&afA[s * 4 + m] =
          *(const i32x4*)(Arow + (long)m * 16 * lda + (s * 4 + g) * 16);
  stageB(Bb, 0, ldb, BsB, tid);

  for (int t = 0; t < nt; t += 2) {
    FS_ITER(afA, afB, t);
    FS_ITER(afB, afA, t + 1);
  }
}

// XCD-bijective swizzle for a 512-block 1D grid over GX x GY tiles
__device__ __forceinline__ void tile_xy(int GX, int& bx, int& by) {
  const int bid = blockIdx.x;                  // 512 % 8 == 0
  const int id = (bid & 7) * 64 + (bid >> 3);
  bx = id & (GX - 1);
  by = id / GX;
}

// ---------------------------------------------------------------------------
// Kernel C: GEMM1 (MX-fp4)  phase = x @ coeff ; epilogue -> fp4 (cos|sin<<4)
// A scale 2^0 (0x7F), B scale 2^-3 (0x7C)
// ---------------------------------------------------------------------------
__global__ __launch_bounds__(256) void gemm_phase(const char* __restrict__ xf4,
                                                  const char* __restrict__ ct4,
                                                  u8* __restrict__ cs4) {
  __shared__ __align__(16) char smem[32768];
  int bx, by;
  tile_xy(16, bx, by);
  const int rowA0 = by * 128;
  const int colB0 = bx * 128;
  f32x4 acc[4][4];
#pragma unroll
  for (int m = 0; m < 4; ++m)
#pragma unroll
    for (int n = 0; n < 4; ++n)
#pragma unroll
      for (int j = 0; j < 4; ++j) acc[m][n][j] = 0.0f;

  gemm_kloop_fp4<0x7F7F7F7F, 0x7C7C7C7C>(xf4, ct4, rowA0, colB0, I_DIM / 2, smem, acc);

  const int lane = threadIdx.x & 63;
  const int wid = threadIdx.x >> 6;
  const int wr = wid >> 1, wc = wid & 1;
#pragma unroll
  for (int m = 0; m < 4; ++m) {
#pragma unroll
    for (int n = 0; n < 4; ++n) {
      const int col = colB0 + wc * 64 + n * 16 + (lane & 15);
#pragma unroll
      for (int j = 0; j < 4; ++j) {
        const int row = rowA0 + wr * 64 + m * 16 + (lane >> 4) * 4 + j;
        const float p = acc[m][n][j];
        const u32 b = f2fp4(__cosf(p), 4.f) | (f2fp4(__sinf(p), 4.f) << 4);
        cs4[(long)row * H_DIM + col] = (u8)b;
      }
    }
  }
}

// ---------------------------------------------------------------------------
// Kernel D: GEMM2 (MX-fp4)  gain = cs4 @ ab4^T + H*bias
// A scale 2^-2 (0x7D), B scale 2^-3 (0x7C)
// ---------------------------------------------------------------------------
__global__ __launch_bounds__(256) void gemm_gain(const char* __restrict__ cs4,
                                                 const char* __restrict__ ab4,
                                                 const float* __restrict__ bias,
                                                 float* __restrict__ out) {
  __shared__ __align__(16) char smem[32768];
  int bx, by;
  tile_xy(16, bx, by);
  const int rowA0 = by * 128;
  const int colB0 = bx * 128;
  f32x4 acc[4][4];
#pragma unroll
  for (int m = 0; m < 4; ++m)
#pragma unroll
    for (int n = 0; n < 4; ++n)
#pragma unroll
      for (int j = 0; j < 4; ++j) acc[m][n][j] = 0.0f;

  gemm_kloop_fp4<0x7D7D7D7D, 0x7C7C7C7C>(cs4, ab4, rowA0, colB0, H_DIM, smem, acc);

  const int lane = threadIdx.x & 63;
  const int wid = threadIdx.x >> 6;
  const int wr = wid >> 1, wc = wid & 1;
#pragma unroll
  for (int m = 0; m < 4; ++m) {
#pragma unroll
    for (int n = 0; n < 4; ++n) {
      const int col = colB0 + wc * 64 + n * 16 + (lane & 15);
      const float bv = 2048.0f * bias[col];
#pragma unroll
      for (int j = 0; j < 4; ++j) {
        const int row = rowA0 + wr * 64 + m * 16 + (lane >> 4) * 4 + j;
        out[(long)row * I_DIM + col] = acc[m][n][j] + bv;
      }
    }
  }
}

// ---------------------------------------------------------------------------
extern "C" void kernel_launch(void* const* d_in, const int* in_sizes, int n_in,
                              void* d_out, int out_size, void* d_ws, size_t ws_size,
                              hipStream_t stream) {
  const float* x     = (const float*)d_in[0];
  const float* coeff = (const float*)d_in[1];
  const float* an    = (const float*)d_in[2];
  const float* bn    = (const float*)d_in[3];
  const float* bias  = (const float*)d_in[4];
  float* out = (float*)d_out;

  char* ws = (char*)d_ws;
  char* xf4 = ws;                        //  4 MB  [B, I/2] fp4 (x, scale 1)
  char* ct4 = ws + (4L << 20);           //  2 MB  [H, I/2] fp4 (coeff^T x8)
  char* ab4 = ws + (8L << 20);           //  4 MB  [I, H]   fp4-pair (an|bn<<4)
  u8*  cs4  = (u8*)(ws + (12L << 20));   //  8 MB  [B, H]   fp4-pair (cos|sin<<4)

  convert_ew<<<1024, 256, 0, stream>>>(x, an, bn, (u16*)xf4, (u32*)ab4);
  transpose_conv<<<dim3(H_DIM / 32, I_DIM / 32), 256, 0, stream>>>(coeff, (u16*)ct4);
  gemm_phase<<<512, 256, 0, stream>>>(xf4, ct4, cs4);
  gemm_gain<<<512, 256, 0, stream>>>((const char*)cs4, (const char*)ab4, bias, out);
}

// Round 10
// 69.957 us; speedup vs baseline: 1.3769x; 1.3769x over previous
//
#include <hip/hip_runtime.h>
#include <hip/hip_bf16.h>

#define B_DIM 4096
#define I_DIM 2048
#define H_DIM 2048

typedef unsigned char u8;
typedef unsigned short u16;
typedef unsigned int u32;
typedef __attribute__((ext_vector_type(4))) float f32x4;
typedef __attribute__((ext_vector_type(4))) int i32x4;
typedef __attribute__((ext_vector_type(8))) int i32x8;

__device__ __forceinline__ void gload_lds16(const void* g, void* l) {
  __builtin_amdgcn_global_load_lds(
      (const __attribute__((address_space(1))) void*)g,
      (__attribute__((address_space(3))) void*)l, 16, 0, 0);
}

// branchless fp4 (e2m1) encoder: quantizes v*inv_scale to e2m1 code
__device__ __forceinline__ u32 f2fp4(float v, float inv_scale) {
  const float a = fabsf(v) * inv_scale;
  u32 m = (u32)(a > 0.25f) + (u32)(a > 0.75f) + (u32)(a > 1.25f) +
          (u32)(a > 1.75f) + (u32)(a > 2.5f) + (u32)(a > 3.5f) + (u32)(a > 5.0f);
  return ((__float_as_uint(v) >> 31) << 3) | m;
}

// ---------------------------------------------------------------------------
// Kernel A: x -> fp4 FRAGMENT-ORDERED xf4f (scale 1);
//           (an,bn) -> fp4-pair byte ab4[I,H] row-major (lo=an, hi=bn; x8)
// Fragment order: byte(row b, kbyte kb) at ((b>>4)*NC + kb>>4)*256 + (b&15)*16
// + (kb&15), NC = Kbytes/16. One thread = one u32 (8 nibbles), lane-consecutive
// writes; reads 128B-contiguous per 4 lanes.
// ---------------------------------------------------------------------------
__global__ void convert_ew(const float* __restrict__ x, const float* __restrict__ an,
                           const float* __restrict__ bn, u32* __restrict__ xf4f,
                           u32* __restrict__ ab4) {
  const long NXU = (long)B_DIM * I_DIM / 8;   // u32s of xf4f (1M)
  const long NAU = (long)I_DIM * H_DIM / 4;   // u32s of ab4 (1M)
  const long total = NXU + NAU;
  for (long u = (long)blockIdx.x * blockDim.x + threadIdx.x; u < total;
       u += (long)gridDim.x * blockDim.x) {
    if (u < NXU) {
      // decode fragment-order index: o4 = which 4B in 16B chunk, r = row&15,
      // c = k-chunk (64 per row for Kbytes=1024), tm = row tile
      const int o4 = (int)(u & 3);
      const int r = (int)((u >> 2) & 15);
      const int c = (int)((u >> 6) & 63);
      const long tm = u >> 12;
      const float* src = x + ((tm * 16 + r) * (long)I_DIM + c * 32 + o4 * 8);
      float4 v0 = *(const float4*)src;
      float4 v1 = *(const float4*)(src + 4);
      u32 w = f2fp4(v0.x, 1.f) | (f2fp4(v0.y, 1.f) << 4) | (f2fp4(v0.z, 1.f) << 8) |
              (f2fp4(v0.w, 1.f) << 12) | (f2fp4(v1.x, 1.f) << 16) |
              (f2fp4(v1.y, 1.f) << 20) | (f2fp4(v1.z, 1.f) << 24) |
              (f2fp4(v1.w, 1.f) << 28);
      xf4f[u] = w;
    } else {
      long p = (u - NXU) * 4;
      float4 va = *(const float4*)(an + p);
      float4 vb = *(const float4*)(bn + p);
      u32 b0 = f2fp4(va.x, 8.f) | (f2fp4(vb.x, 8.f) << 4);
      u32 b1 = f2fp4(va.y, 8.f) | (f2fp4(vb.y, 8.f) << 4);
      u32 b2 = f2fp4(va.z, 8.f) | (f2fp4(vb.z, 8.f) << 4);
      u32 b3 = f2fp4(va.w, 8.f) | (f2fp4(vb.w, 8.f) << 4);
      ab4[p >> 2] = b0 | (b1 << 8) | (b2 << 16) | (b3 << 24);
    }
  }
}

// ---------------------------------------------------------------------------
// Kernel B: coeff [I,H] fp32 -> coeffT fp4 x8 (HW 2^-3), [H, I/2 bytes]
// ---------------------------------------------------------------------------
__global__ void transpose_conv(const float* __restrict__ c, u16* __restrict__ ct4) {
  __shared__ float tile[32][33];
  const int i0 = blockIdx.y * 32;
  const int h0 = blockIdx.x * 32;
  const int tid = threadIdx.x;
  const int tx = tid & 31;
  const int ty = tid >> 5;
  for (int r = ty; r < 32; r += 8)
    tile[r][tx] = c[(long)(i0 + r) * H_DIM + (h0 + tx)];
  __syncthreads();
  const int hl = tid >> 3;
  const int q = (tid & 7) * 4;
  u32 w = f2fp4(tile[q + 0][hl], 8.f) | (f2fp4(tile[q + 1][hl], 8.f) << 4) |
          (f2fp4(tile[q + 2][hl], 8.f) << 8) | (f2fp4(tile[q + 3][hl], 8.f) << 12);
  ct4[(long)(h0 + hl) * (I_DIM / 4) + ((i0 + q) >> 2)] = (u16)w;
}

// ---------------------------------------------------------------------------
// fp4 GEMM K-loop: A fragment-ordered in global, loaded straight to VGPR
// (one coalesced 1KB wave-load per fragment); B row-major, LDS-staged dbuf
// (2x16KB, XOR swizzle), single barrier/iter, depth-1 prefetch of both.
// 128x128 block, 4 waves (2x2), per-wave 64x64.
// ---------------------------------------------------------------------------
__device__ __forceinline__ void stageB(const char* Bb, long kbyte, long ldb,
                                       char* Bdst, int tid) {
#pragma unroll
  for (int i = 0; i < 4; ++i) {
    const int o = i * 4096 + tid * 16;
    const int row = o >> 7;
    const int ls = ((((o >> 4) & 7) ^ (row & 7)) << 4);
    gload_lds16(Bb + (long)row * ldb + kbyte + ls, Bdst + o);
  }
}

__device__ __forceinline__ i32x4 frag_ld16(const char* S, int row, int slot) {
  return *(const i32x4*)(S + row * 128 + ((slot ^ (row & 7)) << 4));
}

#define RA_ITER(CUR, NXT, t)                                                     \
  {                                                                              \
    asm volatile("s_waitcnt vmcnt(0)" ::: "memory");                             \
    __builtin_amdgcn_sched_barrier(0);                                           \
    __builtin_amdgcn_s_barrier();                                                \
    __builtin_amdgcn_sched_barrier(0);                                           \
    const char* Bs = BsB + (((t) & 1) << 14);                                    \
    i32x8 bfr[8];                                                                \
    _Pragma("unroll") for (int s = 0; s < 2; ++s)                                \
      _Pragma("unroll") for (int n = 0; n < 4; ++n)                              \
        *(i32x4*)&bfr[s * 4 + n] = frag_ld16(Bs, brow + n * 16, s * 4 + g);      \
    if ((t) + 1 < nt) {                                                          \
      _Pragma("unroll") for (int s = 0; s < 2; ++s)                              \
        _Pragma("unroll") for (int m = 0; m < 4; ++m)                            \
          *(i32x4*)&NXT[s * 4 + m] = *(const i32x4*)(                            \
              Ap + (long)m * mstride + ((long)(t) + 1) * 2048 + s * 1024);       \
      stageB(Bb, ((long)(t) + 1) * 128, ldb, BsB + ((((t) + 1) & 1) << 14), tid);\
    }                                                                            \
    __builtin_amdgcn_sched_barrier(0);                                           \
    asm volatile("s_waitcnt lgkmcnt(0)" ::: "memory");                           \
    __builtin_amdgcn_sched_barrier(0);                                           \
    __builtin_amdgcn_s_setprio(1);                                               \
    _Pragma("unroll") for (int s = 0; s < 2; ++s)                                \
      _Pragma("unroll") for (int m = 0; m < 4; ++m)                              \
        _Pragma("unroll") for (int n = 0; n < 4; ++n)                            \
          acc[m][n] = __builtin_amdgcn_mfma_scale_f32_16x16x128_f8f6f4(          \
              CUR[s * 4 + m], bfr[s * 4 + n], acc[m][n], 4, 4, 0, SA, 0, SB);    \
    __builtin_amdgcn_s_setprio(0);                                               \
    __builtin_amdgcn_sched_barrier(0);                                           \
  }

template <int SA, int SB>
__device__ __forceinline__ void gemm_kloop_fp4(const char* __restrict__ Afrag,
                                               const char* __restrict__ Bt,
                                               int rowA0, int colB0, long Kbytes,
                                               char* BsB, f32x4 acc[4][4]) {
  const int tid = threadIdx.x;
  const int lane = tid & 63;
  const int wid = tid >> 6;
  const int wr = wid >> 1, wc = wid & 1;
  const long ldb = Kbytes;
  const char* Bb = Bt + (long)colB0 * ldb;
  const long mstride = Kbytes * 16;  // bytes per 16-row fragment tile
  const char* Ap = Afrag + ((long)(rowA0 >> 4) + wr * 4) * mstride + lane * 16;
  const int brow = wc * 64 + (lane & 15);
  const int g = lane >> 4;
  const int nt = (int)(Kbytes >> 7);

  i32x8 aA[8], aB[8];  // named A dbuf, [s*4+m], low i32x4 valid
#pragma unroll
  for (int s = 0; s < 2; ++s)
#pragma unroll
    for (int m = 0; m < 4; ++m)
      *(i32x4*)&aA[s * 4 + m] = *(const i32x4*)(Ap + (long)m * mstride + s * 1024);
  stageB(Bb, 0, ldb, BsB, tid);

  for (int t = 0; t < nt; t += 2) {
    RA_ITER(aA, aB, t);
    RA_ITER(aB, aA, t + 1);
  }
}

// XCD-bijective swizzle for a 512-block 1D grid over GX x GY tiles
__device__ __forceinline__ void tile_xy(int GX, int& bx, int& by) {
  const int bid = blockIdx.x;                  // 512 % 8 == 0
  const int id = (bid & 7) * 64 + (bid >> 3);
  bx = id & (GX - 1);
  by = id / GX;
}

// ---------------------------------------------------------------------------
// Kernel C: GEMM1 (MX-fp4)  phase = x @ coeff ; epilogue -> fragment-ordered
// fp4 (cos|sin<<4) cs4f. A scale 2^0 (0x7F), B scale 2^-3 (0x7C)
// ---------------------------------------------------------------------------
__global__ __launch_bounds__(256) void gemm_phase(const char* __restrict__ xf4f,
                                                  const char* __restrict__ ct4,
                                                  u8* __restrict__ cs4f) {
  __shared__ __align__(16) char smem[32768];
  int bx, by;
  tile_xy(16, bx, by);
  const int rowA0 = by * 128;
  const int colB0 = bx * 128;
  f32x4 acc[4][4];
#pragma unroll
  for (int m = 0; m < 4; ++m)
#pragma unroll
    for (int n = 0; n < 4; ++n)
#pragma unroll
      for (int j = 0; j < 4; ++j) acc[m][n][j] = 0.0f;

  gemm_kloop_fp4<0x7F7F7F7F, 0x7C7C7C7C>(xf4f, ct4, rowA0, colB0, I_DIM / 2, smem, acc);

  const int lane = threadIdx.x & 63;
  const int wid = threadIdx.x >> 6;
  const int wr = wid >> 1, wc = wid & 1;
  // cs4f fragment order (NC = 2048/16 = 128 chunks/row-tile):
  // addr = (tm*128 + c)*256 + r*16 + o
#pragma unroll
  for (int m = 0; m < 4; ++m) {
#pragma unroll
    for (int n = 0; n < 4; ++n) {
      const int col = colB0 + wc * 64 + n * 16 + (lane & 15);
      const int c = col >> 4, o = col & 15;
#pragma unroll
      for (int j = 0; j < 4; ++j) {
        const int row = rowA0 + wr * 64 + m * 16 + (lane >> 4) * 4 + j;
        const int tm = row >> 4, r = row & 15;
        const float p = acc[m][n][j];
        const u32 b = f2fp4(__cosf(p), 4.f) | (f2fp4(__sinf(p), 4.f) << 4);
        cs4f[((long)tm * 128 + c) * 256 + r * 16 + o] = (u8)b;
      }
    }
  }
}

// ---------------------------------------------------------------------------
// Kernel D: GEMM2 (MX-fp4)  gain = cs4f @ ab4^T + H*bias
// A scale 2^-2 (0x7D), B scale 2^-3 (0x7C)
// ---------------------------------------------------------------------------
__global__ __launch_bounds__(256) void gemm_gain(const char* __restrict__ cs4f,
                                                 const char* __restrict__ ab4,
                                                 const float* __restrict__ bias,
                                                 float* __restrict__ out) {
  __shared__ __align__(16) char smem[32768];
  int bx, by;
  tile_xy(16, bx, by);
  const int rowA0 = by * 128;
  const int colB0 = bx * 128;
  f32x4 acc[4][4];
#pragma unroll
  for (int m = 0; m < 4; ++m)
#pragma unroll
    for (int n = 0; n < 4; ++n)
#pragma unroll
      for (int j = 0; j < 4; ++j) acc[m][n][j] = 0.0f;

  gemm_kloop_fp4<0x7D7D7D7D, 0x7C7C7C7C>(cs4f, ab4, rowA0, colB0, H_DIM, smem, acc);

  const int lane = threadIdx.x & 63;
  const int wid = threadIdx.x >> 6;
  const int wr = wid >> 1, wc = wid & 1;
#pragma unroll
  for (int m = 0; m < 4; ++m) {
#pragma unroll
    for (int n = 0; n < 4; ++n) {
      const int col = colB0 + wc * 64 + n * 16 + (lane & 15);
      const float bv = 2048.0f * bias[col];
#pragma unroll
      for (int j = 0; j < 4; ++j) {
        const int row = rowA0 + wr * 64 + m * 16 + (lane >> 4) * 4 + j;
        out[(long)row * I_DIM + col] = acc[m][n][j] + bv;
      }
    }
  }
}

// ---------------------------------------------------------------------------
extern "C" void kernel_launch(void* const* d_in, const int* in_sizes, int n_in,
                              void* d_out, int out_size, void* d_ws, size_t ws_size,
                              hipStream_t stream) {
  const float* x     = (const float*)d_in[0];
  const float* coeff = (const float*)d_in[1];
  const float* an    = (const float*)d_in[2];
  const float* bn    = (const float*)d_in[3];
  const float* bias  = (const float*)d_in[4];
  float* out = (float*)d_out;

  char* ws = (char*)d_ws;
  char* xf4f = ws;                       //  4 MB  fragment-ordered x fp4
  char* ct4  = ws + (4L << 20);          //  2 MB  [H, I/2] fp4 (coeff^T x8)
  char* ab4  = ws + (8L << 20);          //  4 MB  [I, H]   fp4-pair (an|bn<<4)
  u8*  cs4f  = (u8*)(ws + (12L << 20));  //  8 MB  fragment-ordered (cos|sin<<4)

  convert_ew<<<2048, 256, 0, stream>>>(x, an, bn, (u32*)xf4f, (u32*)ab4);
  transpose_conv<<<dim3(H_DIM / 32, I_DIM / 32), 256, 0, stream>>>(coeff, (u16*)ct4);
  gemm_phase<<<512, 256, 0, stream>>>(xf4f, ct4, cs4f);
  gemm_gain<<<512, 256, 0, stream>>>((const char*)cs4f, (const char*)ab4, bias, out);
}

// Round 11
// 67.049 us; speedup vs baseline: 1.4366x; 1.0434x over previous
//
#include <hip/hip_runtime.h>
#include <hip/hip_bf16.h>

#define B_DIM 4096
#define I_DIM 2048
#define H_DIM 2048

typedef unsigned char u8;
typedef unsigned short u16;
typedef unsigned int u32;
typedef __attribute__((ext_vector_type(4))) float f32x4;
typedef __attribute__((ext_vector_type(4))) int i32x4;
typedef __attribute__((ext_vector_type(8))) int i32x8;

__device__ __forceinline__ void gload_lds16(const void* g, void* l) {
  __builtin_amdgcn_global_load_lds(
      (const __attribute__((address_space(1))) void*)g,
      (__attribute__((address_space(3))) void*)l, 16, 0, 0);
}

// branchless fp4 (e2m1) encoder: quantizes v*inv_scale to e2m1 code
__device__ __forceinline__ u32 f2fp4(float v, float inv_scale) {
  const float a = fabsf(v) * inv_scale;
  u32 m = (u32)(a > 0.25f) + (u32)(a > 0.75f) + (u32)(a > 1.25f) +
          (u32)(a > 1.75f) + (u32)(a > 2.5f) + (u32)(a > 3.5f) + (u32)(a > 5.0f);
  return ((__float_as_uint(v) >> 31) << 3) | m;
}

// ---------------------------------------------------------------------------
// Kernel A: x -> fp4 (scale 1) xf4[B, I/2 bytes] row-major;
//           (an,bn) -> fp4-pair byte ab4[I,H] (lo=an, hi=bn; x8, HW 2^-3)
// ---------------------------------------------------------------------------
__global__ void convert_ew(const float* __restrict__ x, const float* __restrict__ an,
                           const float* __restrict__ bn, u16* __restrict__ xf4,
                           u32* __restrict__ ab4) {
  const long NX4 = (long)B_DIM * I_DIM / 4;
  const long NA4 = (long)I_DIM * H_DIM / 4;
  const long total = NX4 + NA4;
  for (long t = (long)blockIdx.x * blockDim.x + threadIdx.x; t < total;
       t += (long)gridDim.x * blockDim.x) {
    if (t < NX4) {
      float4 v = *(const float4*)(x + t * 4);
      u32 b0 = f2fp4(v.x, 1.f) | (f2fp4(v.y, 1.f) << 4);
      u32 b1 = f2fp4(v.z, 1.f) | (f2fp4(v.w, 1.f) << 4);
      xf4[t] = (u16)(b0 | (b1 << 8));
    } else {
      long p = (t - NX4) * 4;
      float4 va = *(const float4*)(an + p);
      float4 vb = *(const float4*)(bn + p);
      u32 b0 = f2fp4(va.x, 8.f) | (f2fp4(vb.x, 8.f) << 4);
      u32 b1 = f2fp4(va.y, 8.f) | (f2fp4(vb.y, 8.f) << 4);
      u32 b2 = f2fp4(va.z, 8.f) | (f2fp4(vb.z, 8.f) << 4);
      u32 b3 = f2fp4(va.w, 8.f) | (f2fp4(vb.w, 8.f) << 4);
      ab4[p >> 2] = b0 | (b1 << 8) | (b2 << 16) | (b3 << 24);
    }
  }
}

// ---------------------------------------------------------------------------
// Kernel B: coeff [I,H] fp32 -> coeffT fp4 x8 (HW 2^-3), [H, I/2 bytes]
// ---------------------------------------------------------------------------
__global__ void transpose_conv(const float* __restrict__ c, u16* __restrict__ ct4) {
  __shared__ float tile[32][33];
  const int i0 = blockIdx.y * 32;
  const int h0 = blockIdx.x * 32;
  const int tid = threadIdx.x;
  const int tx = tid & 31;
  const int ty = tid >> 5;
  for (int r = ty; r < 32; r += 8)
    tile[r][tx] = c[(long)(i0 + r) * H_DIM + (h0 + tx)];
  __syncthreads();
  const int hl = tid >> 3;
  const int q = (tid & 7) * 4;
  u32 w = f2fp4(tile[q + 0][hl], 8.f) | (f2fp4(tile[q + 1][hl], 8.f) << 4) |
          (f2fp4(tile[q + 2][hl], 8.f) << 8) | (f2fp4(tile[q + 3][hl], 8.f) << 12);
  ct4[(long)(h0 + hl) * (I_DIM / 4) + ((i0 + q) >> 2)] = (u16)w;
}

// ---------------------------------------------------------------------------
// fp4 GEMM: BM=128, BN=256, K-step 128 B. 8 waves (2M x 4N), per-wave 64x64.
// Triple-buffered LDS (3 x 48 KB = 144 KB, 1 block/CU), depth-2 prefetch,
// counted vmcnt(6), ONE barrier per iter, XOR-swizzled LDS, setprio MFMA.
// ---------------------------------------------------------------------------
#define NBUF 49152  // per-buffer: A 16 KB @ 0, B 32 KB @ 16384

// stage tile: A 128 rows x 128 B, B 256 rows x 128 B. 6 x 16 B per thread.
__device__ __forceinline__ void stage_tile(const char* Ab, const char* Bb, long kbyte,
                                           long lda, long ldb, char* buf, int tid) {
#pragma unroll
  for (int i = 0; i < 2; ++i) {
    const int o = i * 8192 + tid * 16;
    const int row = o >> 7;
    const int ls = ((((o >> 4) & 7) ^ (row & 7)) << 4);
    gload_lds16(Ab + (long)row * lda + kbyte + ls, buf + o);
  }
#pragma unroll
  for (int i = 0; i < 4; ++i) {
    const int o = i * 8192 + tid * 16;
    const int row = o >> 7;
    const int ls = ((((o >> 4) & 7) ^ (row & 7)) << 4);
    gload_lds16(Bb + (long)row * ldb + kbyte + ls, buf + 16384 + o);
  }
}

__device__ __forceinline__ i32x4 frag_ld16(const char* S, int row, int slot) {
  return *(const i32x4*)(S + row * 128 + ((slot ^ (row & 7)) << 4));
}

template <int SA, int SB>
__device__ __forceinline__ void gemm_kloop_fp4(const char* __restrict__ A,
                                               const char* __restrict__ Bt,
                                               int rowA0, int colB0, long Kbytes,
                                               char* smem, f32x4 acc[4][4]) {
  const int tid = threadIdx.x;
  const int lane = tid & 63;
  const int wid = tid >> 6;   // 0..7
  const int wr = wid >> 2;    // 0..1 (M)
  const int wc = wid & 3;     // 0..3 (N)
  const long lda = Kbytes, ldb = Kbytes;
  const char* Ab = A + (long)rowA0 * lda;
  const char* Bb = Bt + (long)colB0 * ldb;
  const int arow = wr * 64 + (lane & 15);
  const int brow = wc * 64 + (lane & 15);
  const int g = lane >> 4;    // 0..3
  const int nt = (int)(Kbytes >> 7);

  char* b0 = smem;             // tile t (read)
  char* b1 = smem + NBUF;      // tile t+1 (landing)
  char* b2 = smem + 2 * NBUF;  // tile t+2 (stage target, = old t-1)

  stage_tile(Ab, Bb, 0, lda, ldb, b0, tid);
  stage_tile(Ab, Bb, 128, lda, ldb, b1, tid);

  for (int t = 0; t < nt; ++t) {
    // own tile-t stage loads landed (6 of t+1 stay in flight); barrier
    // makes every wave's guarantee collective.
    if (t < nt - 1) asm volatile("s_waitcnt vmcnt(6)" ::: "memory");
    else            asm volatile("s_waitcnt vmcnt(0)" ::: "memory");
    __builtin_amdgcn_sched_barrier(0);
    __builtin_amdgcn_s_barrier();
    __builtin_amdgcn_sched_barrier(0);

    i32x8 af[8], bfr[8];  // low i32x4 used (fp4 operands)
#pragma unroll
    for (int s = 0; s < 2; ++s)
#pragma unroll
      for (int m = 0; m < 4; ++m)
        *(i32x4*)&af[s * 4 + m] = frag_ld16(b0, arow + m * 16, s * 4 + g);
#pragma unroll
    for (int s = 0; s < 2; ++s)
#pragma unroll
      for (int n = 0; n < 4; ++n)
        *(i32x4*)&bfr[s * 4 + n] = frag_ld16(b0 + 16384, brow + n * 16, s * 4 + g);

    // depth-2 prefetch: tile t+2 into the buffer read at t-1 (all waves'
    // t-1 reads drained before they reached the barrier above)
    if (t + 2 < nt)
      stage_tile(Ab, Bb, (long)(t + 2) * 128, lda, ldb, b2, tid);
    __builtin_amdgcn_sched_barrier(0);
    asm volatile("s_waitcnt lgkmcnt(0)" ::: "memory");
    __builtin_amdgcn_sched_barrier(0);

    __builtin_amdgcn_s_setprio(1);
#pragma unroll
    for (int s = 0; s < 2; ++s)
#pragma unroll
      for (int m = 0; m < 4; ++m)
#pragma unroll
        for (int n = 0; n < 4; ++n)
          acc[m][n] = __builtin_amdgcn_mfma_scale_f32_16x16x128_f8f6f4(
              af[s * 4 + m], bfr[s * 4 + n], acc[m][n], 4, 4, 0, SA, 0, SB);
    __builtin_amdgcn_s_setprio(0);
    __builtin_amdgcn_sched_barrier(0);

    char* tmp = b0; b0 = b1; b1 = b2; b2 = tmp;
  }
}

// XCD-bijective swizzle: 256 blocks over 8 (N) x 32 (M) tiles
__device__ __forceinline__ void tile_xy(int& bx, int& by) {
  const int bid = blockIdx.x;                  // 256 % 8 == 0
  const int id = (bid & 7) * 32 + (bid >> 3);
  bx = id & 7;
  by = id >> 3;
}

// ---------------------------------------------------------------------------
// Kernel C: GEMM1 (MX-fp4)  phase = x @ coeff ; epilogue -> fp4 (cos|sin<<4)
// row-major cs4[B,H]. A scale 2^0 (0x7F), B scale 2^-3 (0x7C)
// ---------------------------------------------------------------------------
__global__ __launch_bounds__(512, 1) void gemm_phase(const char* __restrict__ xf4,
                                                     const char* __restrict__ ct4,
                                                     u8* __restrict__ cs4) {
  __shared__ __align__(16) char smem[3 * NBUF];
  int bx, by;
  tile_xy(bx, by);
  const int rowA0 = by * 128;
  const int colB0 = bx * 256;
  f32x4 acc[4][4];
#pragma unroll
  for (int m = 0; m < 4; ++m)
#pragma unroll
    for (int n = 0; n < 4; ++n)
#pragma unroll
      for (int j = 0; j < 4; ++j) acc[m][n][j] = 0.0f;

  gemm_kloop_fp4<0x7F7F7F7F, 0x7C7C7C7C>(xf4, ct4, rowA0, colB0, I_DIM / 2, smem, acc);

  const int lane = threadIdx.x & 63;
  const int wid = threadIdx.x >> 6;
  const int wr = wid >> 2, wc = wid & 3;
#pragma unroll
  for (int m = 0; m < 4; ++m) {
#pragma unroll
    for (int n = 0; n < 4; ++n) {
      const int col = colB0 + wc * 64 + n * 16 + (lane & 15);
#pragma unroll
      for (int j = 0; j < 4; ++j) {
        const int row = rowA0 + wr * 64 + m * 16 + (lane >> 4) * 4 + j;
        const float p = acc[m][n][j];
        const u32 b = f2fp4(__cosf(p), 4.f) | (f2fp4(__sinf(p), 4.f) << 4);
        cs4[(long)row * H_DIM + col] = (u8)b;
      }
    }
  }
}

// ---------------------------------------------------------------------------
// Kernel D: GEMM2 (MX-fp4)  gain = cs4 @ ab4^T + H*bias
// A scale 2^-2 (0x7D), B scale 2^-3 (0x7C)
// ---------------------------------------------------------------------------
__global__ __launch_bounds__(512, 1) void gemm_gain(const char* __restrict__ cs4,
                                                    const char* __restrict__ ab4,
                                                    const float* __restrict__ bias,
                                                    float* __restrict__ out) {
  __shared__ __align__(16) char smem[3 * NBUF];
  int bx, by;
  tile_xy(bx, by);
  const int rowA0 = by * 128;
  const int colB0 = bx * 256;
  f32x4 acc[4][4];
#pragma unroll
  for (int m = 0; m < 4; ++m)
#pragma unroll
    for (int n = 0; n < 4; ++n)
#pragma unroll
      for (int j = 0; j < 4; ++j) acc[m][n][j] = 0.0f;

  gemm_kloop_fp4<0x7D7D7D7D, 0x7C7C7C7C>(cs4, ab4, rowA0, colB0, H_DIM, smem, acc);

  const int lane = threadIdx.x & 63;
  const int wid = threadIdx.x >> 6;
  const int wr = wid >> 2, wc = wid & 3;
#pragma unroll
  for (int m = 0; m < 4; ++m) {
#pragma unroll
    for (int n = 0; n < 4; ++n) {
      const int col = colB0 + wc * 64 + n * 16 + (lane & 15);
      const float bv = 2048.0f * bias[col];
#pragma unroll
      for (int j = 0; j < 4; ++j) {
        const int row = rowA0 + wr * 64 + m * 16 + (lane >> 4) * 4 + j;
        out[(long)row * I_DIM + col] = acc[m][n][j] + bv;
      }
    }
  }
}

// ---------------------------------------------------------------------------
extern "C" void kernel_launch(void* const* d_in, const int* in_sizes, int n_in,
                              void* d_out, int out_size, void* d_ws, size_t ws_size,
                              hipStream_t stream) {
  const float* x     = (const float*)d_in[0];
  const float* coeff = (const float*)d_in[1];
  const float* an    = (const float*)d_in[2];
  const float* bn    = (const float*)d_in[3];
  const float* bias  = (const float*)d_in[4];
  float* out = (float*)d_out;

  char* ws = (char*)d_ws;
  char* xf4 = ws;                        //  4 MB  [B, I/2] fp4 (x, scale 1)
  char* ct4 = ws + (4L << 20);           //  2 MB  [H, I/2] fp4 (coeff^T x8)
  char* ab4 = ws + (8L << 20);           //  4 MB  [I, H]   fp4-pair (an|bn<<4)
  u8*  cs4  = (u8*)(ws + (12L << 20));   //  8 MB  [B, H]   fp4-pair (cos|sin<<4)

  convert_ew<<<1024, 256, 0, stream>>>(x, an, bn, (u16*)xf4, (u32*)ab4);
  transpose_conv<<<dim3(H_DIM / 32, I_DIM / 32), 256, 0, stream>>>(coeff, (u16*)ct4);
  gemm_phase<<<256, 512, 0, stream>>>(xf4, ct4, cs4);
  gemm_gain<<<256, 512, 0, stream>>>((const char*)cs4, (const char*)ab4, bias, out);
}

// Round 12
// 66.157 us; speedup vs baseline: 1.4560x; 1.0135x over previous
//
#include <hip/hip_runtime.h>
#include <hip/hip_bf16.h>

#define B_DIM 4096
#define I_DIM 2048
#define H_DIM 2048

typedef unsigned char u8;
typedef unsigned short u16;
typedef unsigned int u32;
typedef __attribute__((ext_vector_type(4))) float f32x4;
typedef __attribute__((ext_vector_type(4))) int i32x4;
typedef __attribute__((ext_vector_type(8))) int i32x8;

__device__ __forceinline__ void gload_lds16(const void* g, void* l) {
  __builtin_amdgcn_global_load_lds(
      (const __attribute__((address_space(1))) void*)g,
      (__attribute__((address_space(3))) void*)l, 16, 0, 0);
}

// branchless fp4 (e2m1) encoder: quantizes v*inv_scale to e2m1 code
__device__ __forceinline__ u32 f2fp4(float v, float inv_scale) {
  const float a = fabsf(v) * inv_scale;
  u32 m = (u32)(a > 0.25f) + (u32)(a > 0.75f) + (u32)(a > 1.25f) +
          (u32)(a > 1.75f) + (u32)(a > 2.5f) + (u32)(a > 3.5f) + (u32)(a > 5.0f);
  return ((__float_as_uint(v) >> 31) << 3) | m;
}

// ---------------------------------------------------------------------------
// Kernel A (fused prep):
//  blocks [0, 4096):    coeff [I,H] fp32 -> coeffT fp4 x8 (HW 2^-3) ct4[H,I/2]
//  blocks [4096, 5120): x -> fp4 xf4[B,I/2]; (an,bn) -> fp4-pair ab4[I,H]
// ---------------------------------------------------------------------------
__global__ void prep_all(const float* __restrict__ x, const float* __restrict__ coeff,
                         const float* __restrict__ an, const float* __restrict__ bn,
                         u16* __restrict__ xf4, u16* __restrict__ ct4,
                         u32* __restrict__ ab4) {
  if (blockIdx.x < 4096) {
    // transpose tile: 64 x-tiles along H, 64 along I
    __shared__ float tile[32][33];
    const int h0 = (blockIdx.x & 63) * 32;
    const int i0 = (blockIdx.x >> 6) * 32;
    const int tid = threadIdx.x;
    const int tx = tid & 31;
    const int ty = tid >> 5;
    for (int r = ty; r < 32; r += 8)
      tile[r][tx] = coeff[(long)(i0 + r) * H_DIM + (h0 + tx)];
    __syncthreads();
    const int hl = tid >> 3;
    const int q = (tid & 7) * 4;
    u32 w = f2fp4(tile[q + 0][hl], 8.f) | (f2fp4(tile[q + 1][hl], 8.f) << 4) |
            (f2fp4(tile[q + 2][hl], 8.f) << 8) | (f2fp4(tile[q + 3][hl], 8.f) << 12);
    ct4[(long)(h0 + hl) * (I_DIM / 4) + ((i0 + q) >> 2)] = (u16)w;
    return;
  }
  const long NX4 = (long)B_DIM * I_DIM / 4;
  const long NA4 = (long)I_DIM * H_DIM / 4;
  const long total = NX4 + NA4;
  const long stride = (long)1024 * blockDim.x;
  for (long t = (long)(blockIdx.x - 4096) * blockDim.x + threadIdx.x; t < total;
       t += stride) {
    if (t < NX4) {
      float4 v = *(const float4*)(x + t * 4);
      u32 b0 = f2fp4(v.x, 1.f) | (f2fp4(v.y, 1.f) << 4);
      u32 b1 = f2fp4(v.z, 1.f) | (f2fp4(v.w, 1.f) << 4);
      xf4[t] = (u16)(b0 | (b1 << 8));
    } else {
      long p = (t - NX4) * 4;
      float4 va = *(const float4*)(an + p);
      float4 vb = *(const float4*)(bn + p);
      u32 b0 = f2fp4(va.x, 8.f) | (f2fp4(vb.x, 8.f) << 4);
      u32 b1 = f2fp4(va.y, 8.f) | (f2fp4(vb.y, 8.f) << 4);
      u32 b2 = f2fp4(va.z, 8.f) | (f2fp4(vb.z, 8.f) << 4);
      u32 b3 = f2fp4(va.w, 8.f) | (f2fp4(vb.w, 8.f) << 4);
      ab4[p >> 2] = b0 | (b1 << 8) | (b2 << 16) | (b3 << 24);
    }
  }
}

// ---------------------------------------------------------------------------
// fp4 GEMM: 128x128 tile, K-step 128 B, dbuf LDS (64 KB: [A0][B0][A1][B1]),
// depth-2 prefetch, counted vmcnt(8), two barriers/iter (R7-verified),
// XOR-swizzled LDS, setprio MFMA. 4 waves (2x2), per-wave 64x64, 2 blk/CU.
// ---------------------------------------------------------------------------
__device__ __forceinline__ void stage_tile(const char* Ab, const char* Bb, long kbyte,
                                           long lda, long ldb, char* AsB, char* BsB,
                                           int tid) {
#pragma unroll
  for (int i = 0; i < 4; ++i) {
    const int o = i * 4096 + tid * 16;
    const int row = o >> 7;
    const int ls = ((((o >> 4) & 7) ^ (row & 7)) << 4);
    gload_lds16(Ab + (long)row * lda + kbyte + ls, AsB + o);
  }
#pragma unroll
  for (int i = 0; i < 4; ++i) {
    const int o = i * 4096 + tid * 16;
    const int row = o >> 7;
    const int ls = ((((o >> 4) & 7) ^ (row & 7)) << 4);
    gload_lds16(Bb + (long)row * ldb + kbyte + ls, BsB + o);
  }
}

__device__ __forceinline__ i32x4 frag_ld16(const char* S, int row, int slot) {
  return *(const i32x4*)(S + row * 128 + ((slot ^ (row & 7)) << 4));
}

template <int SA, int SB>
__device__ __forceinline__ void gemm_kloop_fp4(const char* __restrict__ A,
                                               const char* __restrict__ Bt,
                                               int rowA0, int colB0, long Kbytes,
                                               char* smem, f32x4 acc[4][4]) {
  const int tid = threadIdx.x;
  const int lane = tid & 63;
  const int wid = tid >> 6;
  const int wr = wid >> 1, wc = wid & 1;
  const long lda = Kbytes, ldb = Kbytes;
  const char* Ab = A + (long)rowA0 * lda;
  const char* Bb = Bt + (long)colB0 * ldb;
  const int arow = wr * 64 + (lane & 15);
  const int brow = wc * 64 + (lane & 15);
  const int g = lane >> 4;  // 0..3
  const int nt = (int)(Kbytes >> 7);
  char* AsB = smem;           // A tiles @ 0, 32768
  char* BsB = smem + 16384;   // B tiles @ 16384, 49152

  stage_tile(Ab, Bb, 0, lda, ldb, AsB, BsB, tid);
  stage_tile(Ab, Bb, 128, lda, ldb, AsB + 32768, BsB + 32768, tid);

  for (int t = 0; t < nt; ++t) {
    const int cur = (t & 1) << 15;
    if (t < nt - 1) asm volatile("s_waitcnt vmcnt(8)" ::: "memory");
    else            asm volatile("s_waitcnt vmcnt(0)" ::: "memory");
    __builtin_amdgcn_sched_barrier(0);
    __builtin_amdgcn_s_barrier();
    __builtin_amdgcn_sched_barrier(0);

    i32x8 af[8], bfr[8];  // low i32x4 holds the fp4 operand
#pragma unroll
    for (int s = 0; s < 2; ++s)
#pragma unroll
      for (int m = 0; m < 4; ++m) {
        *(i32x4*)&af[s * 4 + m]  = frag_ld16(AsB + cur, arow + m * 16, s * 4 + g);
        *(i32x4*)&bfr[s * 4 + m] = frag_ld16(BsB + cur, brow + m * 16, s * 4 + g);
      }
    asm volatile("s_waitcnt lgkmcnt(0)" ::: "memory");
    __builtin_amdgcn_sched_barrier(0);
    __builtin_amdgcn_s_barrier();  // all waves done reading buf[cur]
    __builtin_amdgcn_sched_barrier(0);

    if (t + 2 < nt)
      stage_tile(Ab, Bb, (long)(t + 2) * 128, lda, ldb, AsB + cur, BsB + cur, tid);

    __builtin_amdgcn_s_setprio(1);
#pragma unroll
    for (int s = 0; s < 2; ++s)
#pragma unroll
      for (int m = 0; m < 4; ++m)
#pragma unroll
        for (int n = 0; n < 4; ++n)
          acc[m][n] = __builtin_amdgcn_mfma_scale_f32_16x16x128_f8f6f4(
              af[s * 4 + m], bfr[s * 4 + n], acc[m][n], 4, 4, 0, SA, 0, SB);
    __builtin_amdgcn_s_setprio(0);
    __builtin_amdgcn_sched_barrier(0);
  }
}

// Square XCD chunking: 512 blocks over 32(by) x 16(bx); each XCD owns an
// 8x8 square chunk -> per-XCD working set fits the 4 MB L2.
__device__ __forceinline__ void tile_xy(int& bx, int& by) {
  const int bid = blockIdx.x;        // 0..511, 512 % 8 == 0
  const int xcd = bid & 7;
  const int loc = bid >> 3;          // 0..63
  const int cy = xcd >> 1;           // 0..3  chunk row
  const int cx = xcd & 1;            // 0..1  chunk col
  by = cy * 8 + (loc >> 3);          // 0..31
  bx = cx * 8 + (loc & 7);           // 0..15
}

// ---------------------------------------------------------------------------
// Kernel C: GEMM1 (MX-fp4)  phase = x @ coeff ; epilogue -> fp4 (cos|sin<<4)
// A scale 2^0 (0x7F), B scale 2^-3 (0x7C)
// ---------------------------------------------------------------------------
__global__ __launch_bounds__(256) void gemm_phase(const char* __restrict__ xf4,
                                                  const char* __restrict__ ct4,
                                                  u8* __restrict__ cs4) {
  __shared__ __align__(16) char smem[65536];
  int bx, by;
  tile_xy(bx, by);
  const int rowA0 = by * 128;
  const int colB0 = bx * 128;
  f32x4 acc[4][4];
#pragma unroll
  for (int m = 0; m < 4; ++m)
#pragma unroll
    for (int n = 0; n < 4; ++n)
#pragma unroll
      for (int j = 0; j < 4; ++j) acc[m][n][j] = 0.0f;

  gemm_kloop_fp4<0x7F7F7F7F, 0x7C7C7C7C>(xf4, ct4, rowA0, colB0, I_DIM / 2, smem, acc);

  const int lane = threadIdx.x & 63;
  const int wid = threadIdx.x >> 6;
  const int wr = wid >> 1, wc = wid & 1;
#pragma unroll
  for (int m = 0; m < 4; ++m) {
#pragma unroll
    for (int n = 0; n < 4; ++n) {
      const int col = colB0 + wc * 64 + n * 16 + (lane & 15);
#pragma unroll
      for (int j = 0; j < 4; ++j) {
        const int row = rowA0 + wr * 64 + m * 16 + (lane >> 4) * 4 + j;
        const float p = acc[m][n][j];
        const u32 b = f2fp4(__cosf(p), 4.f) | (f2fp4(__sinf(p), 4.f) << 4);
        cs4[(long)row * H_DIM + col] = (u8)b;
      }
    }
  }
}

// ---------------------------------------------------------------------------
// Kernel D: GEMM2 (MX-fp4)  gain = cs4 @ ab4^T + H*bias
// A scale 2^-2 (0x7D), B scale 2^-3 (0x7C)
// ---------------------------------------------------------------------------
__global__ __launch_bounds__(256) void gemm_gain(const char* __restrict__ cs4,
                                                 const char* __restrict__ ab4,
                                                 const float* __restrict__ bias,
                                                 float* __restrict__ out) {
  __shared__ __align__(16) char smem[65536];
  int bx, by;
  tile_xy(bx, by);
  const int rowA0 = by * 128;
  const int colB0 = bx * 128;
  f32x4 acc[4][4];
#pragma unroll
  for (int m = 0; m < 4; ++m)
#pragma unroll
    for (int n = 0; n < 4; ++n)
#pragma unroll
      for (int j = 0; j < 4; ++j) acc[m][n][j] = 0.0f;

  gemm_kloop_fp4<0x7D7D7D7D, 0x7C7C7C7C>(cs4, ab4, rowA0, colB0, H_DIM, smem, acc);

  const int lane = threadIdx.x & 63;
  const int wid = threadIdx.x >> 6;
  const int wr = wid >> 1, wc = wid & 1;
#pragma unroll
  for (int m = 0; m < 4; ++m) {
#pragma unroll
    for (int n = 0; n < 4; ++n) {
      const int col = colB0 + wc * 64 + n * 16 + (lane & 15);
      const float bv = 2048.0f * bias[col];
#pragma unroll
      for (int j = 0; j < 4; ++j) {
        const int row = rowA0 + wr * 64 + m * 16 + (lane >> 4) * 4 + j;
        out[(long)row * I_DIM + col] = acc[m][n][j] + bv;
      }
    }
  }
}

// ---------------------------------------------------------------------------
extern "C" void kernel_launch(void* const* d_in, const int* in_sizes, int n_in,
                              void* d_out, int out_size, void* d_ws, size_t ws_size,
                              hipStream_t stream) {
  const float* x     = (const float*)d_in[0];
  const float* coeff = (const float*)d_in[1];
  const float* an    = (const float*)d_in[2];
  const float* bn    = (const float*)d_in[3];
  const float* bias  = (const float*)d_in[4];
  float* out = (float*)d_out;

  char* ws = (char*)d_ws;
  char* xf4 = ws;                        //  4 MB  [B, I/2] fp4 (x, scale 1)
  char* ct4 = ws + (4L << 20);           //  2 MB  [H, I/2] fp4 (coeff^T x8)
  char* ab4 = ws + (8L << 20);           //  4 MB  [I, H]   fp4-pair (an|bn<<4)
  u8*  cs4  = (u8*)(ws + (12L << 20));   //  8 MB  [B, H]   fp4-pair (cos|sin<<4)

  prep_all<<<5120, 256, 0, stream>>>(x, coeff, an, bn, (u16*)xf4, (u16*)ct4,
                                     (u32*)ab4);
  gemm_phase<<<512, 256, 0, stream>>>(xf4, ct4, cs4);
  gemm_gain<<<512, 256, 0, stream>>>((const char*)cs4, (const char*)ab4, bias, out);
}